// Round 2
// baseline (830.625 us; speedup 1.0000x reference)
//
#include <hip/hip_runtime.h>
#include <hip/hip_bf16.h>
#include <stdint.h>

// ---------------------------------------------------------------------------
// CharToWord: bidirectional char-GRU + attention pooling, MFMA bf16 pipeline.
// v2: gru = 512-thread blocks, 2 independent word-groups sharing Whh in LDS
//     (8 waves/CU instead of 4), bf16 xp table (1 uint4 per word-step),
//     chars pre-remapped for backward dir at staging time.
//     attn = staged regs reused for facc (no LDS re-read), 2 barriers/t.
// ---------------------------------------------------------------------------

typedef unsigned short u16;
typedef float f32x4 __attribute__((ext_vector_type(4)));
typedef __bf16 bf16x8 __attribute__((ext_vector_type(8)));

#if __has_builtin(__builtin_amdgcn_exp2f)
#define EXP2F(x) __builtin_amdgcn_exp2f(x)
#else
#define EXP2F(x) exp2f(x)
#endif
#if __has_builtin(__builtin_amdgcn_rcpf)
#define RCPF(x) __builtin_amdgcn_rcpf(x)
#else
#define RCPF(x) (1.0f / (x))
#endif

#define LOG2E 1.4426950408889634f

__device__ __forceinline__ u16 f2b(float f) {
  uint32_t u = __builtin_bit_cast(uint32_t, f);
  u = u + 0x7FFFu + ((u >> 16) & 1u);
  return (u16)(u >> 16);
}
__device__ __forceinline__ float b2f(u16 s) {
  uint32_t u = ((uint32_t)s) << 16;
  return __builtin_bit_cast(float, u);
}
__device__ __forceinline__ float fast_sig(float x) {
  return RCPF(1.0f + EXP2F(-LOG2E * x));
}
__device__ __forceinline__ float fast_tanh(float x) {
  return 1.0f - 2.0f * RCPF(EXP2F(2.0f * LOG2E * x) + 1.0f);
}

// ---------------------------------------------------------------------------
// prep: grid 576 x 256
//  blocks [0,512)   : xp tables (bf16), layout [c][wv*16+col][8] (idx cls*2+j2)
//  blocks [512,560) : Whh frag bf16, chunks ((nt*4+kt)*64+lane)*8
//  blocks [560,576) : Wp frag bf16,  chunks ((nt*8+kt)*64+lane)*8
// ---------------------------------------------------------------------------
__global__ void prep_kernel(
    const float* __restrict__ emb,
    const float* __restrict__ wih_f, const float* __restrict__ bih_f,
    const float* __restrict__ wih_b, const float* __restrict__ bih_b,
    const float* __restrict__ whh_f_in, const float* __restrict__ whh_b_in,
    const float* __restrict__ wp_in,
    u16* __restrict__ xpb_f, u16* __restrict__ xpb_b,
    u16* __restrict__ whhf, u16* __restrict__ whhb, u16* __restrict__ wpf) {
  int gid = blockIdx.x * 256 + threadIdx.x;
  if (blockIdx.x < 512) {
    int d = gid >> 16;          // 65536 entries per direction
    int r = gid & 65535;
    int c = r >> 9;             // 512 per char
    int r2 = r & 511;
    int wc = r2 >> 3;           // wv*16 + col
    int i8 = r2 & 7;
    float v = 0.f;
    if (i8 < 6) {
      int cls = i8 >> 1, j2 = i8 & 1;
      int gate = cls * 128 + (wc >> 4) * 32 + j2 * 16 + (wc & 15);
      const float* wih = d ? wih_b : wih_f;
      const float* bih = d ? bih_b : bih_f;
      float s = 0.f;
      for (int e = 0; e < 64; e++) s += emb[c * 64 + e] * wih[gate * 64 + e];
      v = s + bih[gate];
    }
    (d ? xpb_b : xpb_f)[(c << 9) + r2] = f2b(v);
  } else if (blockIdx.x < 560) {
    int idx = gid - 512 * 256;  // 0..12287
    int d = (idx >= 6144) ? 1 : 0;
    int r = idx - d * 6144;
    int lane = r & 63, kt = (r >> 6) & 3, nt = r >> 8;
    int n = nt * 16 + (lane & 15);
    int k0 = kt * 32 + (lane >> 4) * 8;
    const float* w = d ? whh_b_in : whh_f_in;
    u16* o = (d ? whhb : whhf) + r * 8;
    for (int j = 0; j < 8; j++) o[j] = f2b(w[n * 128 + k0 + j]);
  } else {
    int idx = gid - 560 * 256;  // 0..4095
    if (idx < 4096) {
      int lane = idx & 63, kt = (idx >> 6) & 7, nt = idx >> 9;
      int n = nt * 16 + (lane & 15);
      int k0 = kt * 32 + (lane >> 4) * 8;
      u16* o = wpf + idx * 8;
      for (int j = 0; j < 8; j++) o[j] = f2b(wp_in[n * 256 + k0 + j]);
    }
  }
}

// ---------------------------------------------------------------------------
// gru: grid 2*blocks_per_dir x 512. Block = one direction, TWO independent
// 64-word groups (4 waves each) sharing one Whh LDS copy.
// Wave wv owns gate triples hid in [wv*32,+32): n_tiles cls*8 + wv*2 + j2.
// ---------------------------------------------------------------------------
__global__ __launch_bounds__(512, 2) void gru_kernel(
    const int* __restrict__ chars, const int* __restrict__ lens,
    const u16* __restrict__ xpb_f, const u16* __restrict__ xpb_b,
    const u16* __restrict__ whhf, const u16* __restrict__ whhb,
    const float* __restrict__ bhh_f, const float* __restrict__ bhh_b,
    u16* __restrict__ hf, u16* __restrict__ hb, int word_off, int cb,
    int blocks_per_dir) {
  const int b = blockIdx.x;
  const int dir = (b >= blocks_per_dir) ? 1 : 0;
  const int wpair = b - dir * blocks_per_dir;
  const int tid = threadIdx.x;
  const int g = tid >> 8;        // group 0/1
  const int tg = tid & 255;      // thread-in-group
  int wg = wpair * 2 + g;
  const bool wvalid = (wg < cb);
  if (!wvalid) wg = cb - 1;
  const int gw0 = word_off + wg * 64;

  const u16* xp = dir ? xpb_b : xpb_f;
  const u16* whh = dir ? whhb : whhf;
  const float* bhh = dir ? bhh_b : bhh_f;
  u16* hout = (dir ? hb : hf) + (size_t)wg * 64 * 20 * 128;

  __shared__ u16 whh_s[49152];              // 96 KiB (one direction)
  __shared__ u16 h_s[2][8192];              // 2 x 16 KiB, A-frag layout
  __shared__ unsigned char chars_s[2][1280];  // pre-remapped chars [s][w]
  __shared__ unsigned char lens_s[2][64];

  // ---- staging ----
  {
    const uint4* src = (const uint4*)whh;
    uint4* dst = (uint4*)whh_s;
#pragma unroll
    for (int i = 0; i < 12; i++) dst[tid + i * 512] = src[tid + i * 512];
  }
  for (int i = tg; i < 1280; i += 256) {
    int w = i & 63, s = i >> 6;
    int L = lens[gw0 + w];
    int t = dir ? ((s < L) ? (L - 1 - s) : s) : s;
    chars_s[g][s * 64 + w] = (unsigned char)chars[(gw0 + w) * 20 + t];
  }
  if (tg < 64) lens_s[g][tg] = (unsigned char)lens[gw0 + tg];
  {
    uint32_t* hz = (uint32_t*)h_s[g];
    for (int i = tg; i < 4096; i += 256) hz[i] = 0u;
  }
  __syncthreads();

  const int wv = tg >> 6;        // wave within group
  const int ln = tid & 63;
  const int col = ln & 15;
  const int grp = ln >> 4;

  float bh[6];
#pragma unroll
  for (int n = 0; n < 6; n++) {
    int cls = n >> 1, j2 = n & 1;
    bh[n] = bhh[cls * 128 + wv * 32 + j2 * 16 + col];
  }

  const int cw = tg & 15;        // copy-phase word-within-tile
  int Lc[4];
#pragma unroll
  for (int q = 0; q < 4; q++) Lc[q] = lens_s[g][q * 16 + cw];

  float h[4][4][2];
#pragma unroll
  for (int m = 0; m < 4; m++)
#pragma unroll
    for (int r = 0; r < 4; r++) {
      h[m][r][0] = 0.f;
      h[m][r][1] = 0.f;
    }

  for (int s = 0; s < 20; s++) {
    // ---- xp fetch: 1 uint4 (8 bf16) per (m,r) word; chars pre-remapped ----
    uint4 xq[16];
#pragma unroll
    for (int m = 0; m < 4; m++) {
#pragma unroll
      for (int r = 0; r < 4; r++) {
        int w = m * 16 + grp * 4 + r;
        int c = chars_s[g][s * 64 + w];
        xq[m * 4 + r] =
            *(const uint4*)(xp + (((c << 6) + (wv << 4) + col) << 3));
      }
    }

    // ---- hp = h @ Whh^T + bhh via MFMA ----
    f32x4 acc[6][4];
#pragma unroll
    for (int n = 0; n < 6; n++)
#pragma unroll
      for (int m = 0; m < 4; m++) acc[n][m] = (f32x4){bh[n], bh[n], bh[n], bh[n]};

#pragma unroll
    for (int kt = 0; kt < 4; kt++) {
      bf16x8 Af[4];
#pragma unroll
      for (int m = 0; m < 4; m++)
        Af[m] = *(const bf16x8*)(h_s[g] + (((m * 4 + kt) * 64 + ln) << 3));
#pragma unroll
      for (int n = 0; n < 6; n++) {
        int cls = n >> 1, j2 = n & 1;
        int nt = cls * 8 + wv * 2 + j2;
        bf16x8 Bf = *(const bf16x8*)(whh_s + (((nt * 4 + kt) * 64 + ln) << 3));
#pragma unroll
        for (int m = 0; m < 4; m++)
          acc[n][m] = __builtin_amdgcn_mfma_f32_16x16x32_bf16(Af[m], Bf, acc[n][m], 0, 0, 0);
      }
    }

    __syncthreads();  // all reads of h_s done (both groups in lockstep)

    // ---- gates + h update + write h_s (A-frag layout, bf16) ----
#pragma unroll
    for (int m = 0; m < 4; m++) {
#pragma unroll
      for (int r = 0; r < 4; r++) {
        const u16* e = (const u16*)&xq[m * 4 + r];
#pragma unroll
        for (int j2 = 0; j2 < 2; j2++) {
          float rr = fast_sig(b2f(e[j2]) + acc[j2][m][r]);
          float zz = fast_sig(b2f(e[2 + j2]) + acc[2 + j2][m][r]);
          float nn = fast_tanh(b2f(e[4 + j2]) + rr * acc[4 + j2][m][r]);
          float hn = (1.f - zz) * nn + zz * h[m][r][j2];
          h[m][r][j2] = hn;
          int hid3 = j2 * 2 + (col >> 3);
          int lane_a = (grp * 4 + r) | (hid3 << 4);
          h_s[g][(((m * 4 + wv) * 64 + lane_a) << 3) + (col & 7)] = f2b(hn);
        }
      }
    }
    __syncthreads();  // h_s complete

    // ---- bulk copy h_s -> global (masked; backward remaps t) ----
    if (wvalid) {
      const int k = wv * 32 + grp * 8;
#pragma unroll
      for (int q = 0; q < 4; q++) {
        int w = q * 16 + cw;
        int L = Lc[q];
        int tdst = dir ? ((s < L) ? (L - 1 - s) : s) : s;
        uint4 v;
        if (s >= L) {
          v = make_uint4(0u, 0u, 0u, 0u);
        } else {
          v = *(const uint4*)(h_s[g] + (((q * 4 + wv) * 64 + ln) << 3));
        }
        *(uint4*)(hout + ((size_t)w * 20 + tdst) * 128 + k) = v;
      }
    }
  }
}

// ---------------------------------------------------------------------------
// attn: grid cb x 256. 64 words/block. Online softmax, single read pass.
// Staged registers reused for the facc update (no LDS re-read).
// ---------------------------------------------------------------------------
__global__ __launch_bounds__(256, 2) void attn_kernel(
    const u16* __restrict__ hf, const u16* __restrict__ hb,
    const u16* __restrict__ wpf,
    const float* __restrict__ bp, const float* __restrict__ ctx,
    float* __restrict__ out, int word_off) {
  const int blk = blockIdx.x;
  const int lw0 = blk * 64;

  __shared__ u16 ot_s[16384];      // 32 KiB: Out_t frag layout
  __shared__ float part_s[4][64];  // per-wave score partials

  const int tid = threadIdx.x;
  const int wv = tid >> 6, ln = tid & 63, col = ln & 15, grp = ln >> 4;
  const int sw = tid >> 2;   // this thread's word (4 threads per word)
  const int seg = tid & 3;   // 64-dim segment of the 256-dim output

  float bpv[2], ctxv[2];
#pragma unroll
  for (int n = 0; n < 2; n++) {
    int nt = wv + n * 4;
    bpv[n] = bp[nt * 16 + col];
    ctxv[n] = ctx[nt * 16 + col];
  }

  float facc[64];
#pragma unroll
  for (int i = 0; i < 64; i++) facc[i] = 0.f;
  float mrun = -3.0e38f, drun = 0.f;

  const u16* srcbase =
      ((seg < 2) ? hf : hb) + (size_t)(lw0 + sw) * 2560 + (seg & 1) * 64;

  for (int t = 0; t < 20; t++) {
    // stage Out_t into frag layout; keep own-word data in regs
    uint4 v[8];
    {
      const u16* src = srcbase + t * 128;
#pragma unroll
      for (int q = 0; q < 8; q++) {
        v[q] = *(const uint4*)(src + q * 8);
        int kt = seg * 2 + (q >> 2);
        int lane_a = (sw & 15) | ((q & 3) << 4);
        int m = sw >> 4;
        *(uint4*)(ot_s + (((m * 8 + kt) * 64 + lane_a) << 3)) = v[q];
      }
    }
    __syncthreads();

    // proj = Out_t @ Wp^T + bp  (Wp frags straight from L2)
    f32x4 acc[2][4];
#pragma unroll
    for (int n = 0; n < 2; n++)
#pragma unroll
      for (int m = 0; m < 4; m++) acc[n][m] = (f32x4){bpv[n], bpv[n], bpv[n], bpv[n]};

#pragma unroll
    for (int kt = 0; kt < 8; kt++) {
      bf16x8 Af[4];
#pragma unroll
      for (int m = 0; m < 4; m++)
        Af[m] = *(const bf16x8*)(ot_s + (((m * 8 + kt) * 64 + ln) << 3));
#pragma unroll
      for (int n = 0; n < 2; n++) {
        int nt = wv + n * 4;
        bf16x8 Bf = *(const bf16x8*)(wpf + (((nt * 8 + kt) * 64 + ln) << 3));
#pragma unroll
        for (int m = 0; m < 4; m++)
          acc[n][m] = __builtin_amdgcn_mfma_f32_16x16x32_bf16(Af[m], Bf, acc[n][m], 0, 0, 0);
      }
    }

    // score partials: sum_c tanh(proj)*ctx, reduce over 16 cols, 4 waves
#pragma unroll
    for (int m = 0; m < 4; m++) {
#pragma unroll
      for (int r = 0; r < 4; r++) {
        float p = fast_tanh(acc[0][m][r]) * ctxv[0] +
                  fast_tanh(acc[1][m][r]) * ctxv[1];
        p += __shfl_xor(p, 1, 64);
        p += __shfl_xor(p, 2, 64);
        p += __shfl_xor(p, 4, 64);
        p += __shfl_xor(p, 8, 64);
        if (col == 0) part_s[wv][m * 16 + grp * 4 + r] = p;
      }
    }
    __syncthreads();

    float sc = part_s[0][sw] + part_s[1][sw] + part_s[2][sw] + part_s[3][sw];

    // online softmax update of (m, d, facc) from staged regs
    float mnew = fmaxf(mrun, sc);
    float scale = EXP2F(LOG2E * (mrun - mnew));  // 0 on first iter
    float e = EXP2F(LOG2E * (sc - mnew));
    drun = drun * scale + e;
    mrun = mnew;
#pragma unroll
    for (int q = 0; q < 8; q++) {
      const u16* pv = (const u16*)&v[q];
#pragma unroll
      for (int j = 0; j < 8; j++)
        facc[q * 8 + j] = facc[q * 8 + j] * scale + e * b2f(pv[j]);
    }
  }

  float inv = RCPF(drun);
  float* dst = out + (size_t)(word_off + lw0 + sw) * 256 + seg * 64;
#pragma unroll
  for (int i = 0; i < 64; i++) dst[i] = facc[i] * inv;
}

// ---------------------------------------------------------------------------
extern "C" void kernel_launch(void* const* d_in, const int* in_sizes, int n_in,
                              void* d_out, int out_size, void* d_ws, size_t ws_size,
                              hipStream_t stream) {
  const int* chars = (const int*)d_in[0];
  const int* lens = (const int*)d_in[1];
  const float* emb = (const float*)d_in[2];
  const float* wih_f = (const float*)d_in[3];
  const float* whh_f = (const float*)d_in[4];
  const float* bih_f = (const float*)d_in[5];
  const float* bhh_f = (const float*)d_in[6];
  const float* wih_b = (const float*)d_in[7];
  const float* whh_b = (const float*)d_in[8];
  const float* bih_b = (const float*)d_in[9];
  const float* bhh_b = (const float*)d_in[10];
  const float* wp = (const float*)d_in[11];
  const float* bp = (const float*)d_in[12];
  const float* ctx = (const float*)d_in[13];
  float* outp = (float*)d_out;

  uint8_t* ws = (uint8_t*)d_ws;
  u16* xpb_f = (u16*)(ws + 0);                // 128 KiB
  u16* xpb_b = (u16*)(ws + 131072);           // 128 KiB
  u16* whhf = (u16*)(ws + 262144);            // 96 KiB
  u16* whhb = (u16*)(ws + 360448);            // 96 KiB
  u16* wpf = (u16*)(ws + 458752);             // 64 KiB
  const size_t H_OFF = 524288;

  prep_kernel<<<576, 256, 0, stream>>>(emb, wih_f, bih_f, wih_b, bih_b, whh_f,
                                       whh_b, wp, xpb_f, xpb_b, whhf, whhb, wpf);

  const size_t per_block = (size_t)64 * 20 * 128 * 2 * 2;  // hf+hb bytes / group
  size_t avail = (ws_size > H_OFF) ? (ws_size - H_OFF) : 0;
  int maxcb = (int)(avail / per_block);
  if (maxcb > 512) maxcb = 512;
  maxcb &= ~1;               // keep even so both groups in a block are valid
  if (maxcb < 2) maxcb = 2;  // assume ws >= ~1.9 MiB

  for (int done = 0; done < 512;) {
    int cb = (512 - done < maxcb) ? (512 - done) : maxcb;
    u16* hfp = (u16*)(ws + H_OFF);
    u16* hbp = hfp + (size_t)cb * 64 * 20 * 128;
    int bpd = (cb + 1) >> 1;
    gru_kernel<<<2 * bpd, 512, 0, stream>>>(chars, lens, xpb_f, xpb_b, whhf,
                                            whhb, bhh_f, bhh_b, hfp, hbp,
                                            done * 64, cb, bpd);
    attn_kernel<<<cb, 256, 0, stream>>>(hfp, hbp, wpf, bp, ctx, outp, done * 64);
    done += cb;
  }
}

// Round 4
// 440.460 us; speedup vs baseline: 1.8858x; 1.8858x over previous
//
#include <hip/hip_runtime.h>
#include <hip/hip_bf16.h>
#include <stdint.h>

// ---------------------------------------------------------------------------
// CharToWord v4: bidirectional char-GRU + attention pooling.
//  - counting sort by length: blocks are length-uniform -> loop only L steps,
//    store/read only t < L rows of h (0.54x compute & traffic).
//  - gru: 16 words/block, 4 waves; Whh MFMA B-fragments in VGPRs (96/thread,
//    loaded once from L2 frag table); h exchange via 4 KiB LDS; no spills.
//  - attn: online softmax over valid t, PLUS the reference's pad mass:
//    softmax runs over all 20 positions in the reference; pad rows are zero
//    vectors with constant score c0 = sum tanh(bp)*ctx -> add (20-L)*e^{c0}
//    to the denominator analytically (v3 bug: this mass was dropped).
// ---------------------------------------------------------------------------

typedef unsigned short u16;
typedef float f32x4 __attribute__((ext_vector_type(4)));
typedef __bf16 bf16x8 __attribute__((ext_vector_type(8)));

#if __has_builtin(__builtin_amdgcn_exp2f)
#define EXP2F(x) __builtin_amdgcn_exp2f(x)
#else
#define EXP2F(x) exp2f(x)
#endif
#if __has_builtin(__builtin_amdgcn_rcpf)
#define RCPF(x) __builtin_amdgcn_rcpf(x)
#else
#define RCPF(x) (1.0f / (x))
#endif

#define LOG2E 1.4426950408889634f

__device__ __forceinline__ u16 f2b(float f) {
  uint32_t u = __builtin_bit_cast(uint32_t, f);
  u = u + 0x7FFFu + ((u >> 16) & 1u);
  return (u16)(u >> 16);
}
__device__ __forceinline__ float b2f(u16 s) {
  uint32_t u = ((uint32_t)s) << 16;
  return __builtin_bit_cast(float, u);
}
__device__ __forceinline__ float fast_sig(float x) {
  return RCPF(1.0f + EXP2F(-LOG2E * x));
}
__device__ __forceinline__ float fast_tanh(float x) {
  return 1.0f - 2.0f * RCPF(EXP2F(2.0f * LOG2E * x) + 1.0f);
}

// ---------------------------------------------------------------------------
// prep: grid 576 x 256
//  blocks [0,512)   : xp tables (bf16), layout [c][wv*16+col][8] (idx cls*2+j2)
//  blocks [512,560) : Whh frag bf16, chunks ((nt*4+kt)*64+lane)*8
//  blocks [560,576) : Wp frag bf16,  chunks ((nt*8+kt)*64+lane)*8
// ---------------------------------------------------------------------------
__global__ void prep_kernel(
    const float* __restrict__ emb,
    const float* __restrict__ wih_f, const float* __restrict__ bih_f,
    const float* __restrict__ wih_b, const float* __restrict__ bih_b,
    const float* __restrict__ whh_f_in, const float* __restrict__ whh_b_in,
    const float* __restrict__ wp_in,
    u16* __restrict__ xpb_f, u16* __restrict__ xpb_b,
    u16* __restrict__ whhf, u16* __restrict__ whhb, u16* __restrict__ wpf) {
  int gid = blockIdx.x * 256 + threadIdx.x;
  if (blockIdx.x < 512) {
    int d = gid >> 16;          // 65536 entries per direction
    int r = gid & 65535;
    int c = r >> 9;             // 512 per char
    int r2 = r & 511;
    int wc = r2 >> 3;           // wv*16 + col
    int i8 = r2 & 7;
    float v = 0.f;
    if (i8 < 6) {
      int cls = i8 >> 1, j2 = i8 & 1;
      int gate = cls * 128 + (wc >> 4) * 32 + j2 * 16 + (wc & 15);
      const float* wih = d ? wih_b : wih_f;
      const float* bih = d ? bih_b : bih_f;
      float s = 0.f;
      for (int e = 0; e < 64; e++) s += emb[c * 64 + e] * wih[gate * 64 + e];
      v = s + bih[gate];
    }
    (d ? xpb_b : xpb_f)[(c << 9) + r2] = f2b(v);
  } else if (blockIdx.x < 560) {
    int idx = gid - 512 * 256;  // 0..12287
    int d = (idx >= 6144) ? 1 : 0;
    int r = idx - d * 6144;
    int lane = r & 63, kt = (r >> 6) & 3, nt = r >> 8;
    int n = nt * 16 + (lane & 15);
    int k0 = kt * 32 + (lane >> 4) * 8;
    const float* w = d ? whh_b_in : whh_f_in;
    u16* o = (d ? whhb : whhf) + r * 8;
    for (int j = 0; j < 8; j++) o[j] = f2b(w[n * 128 + k0 + j]);
  } else {
    int idx = gid - 560 * 256;  // 0..4095
    if (idx < 4096) {
      int lane = idx & 63, kt = (idx >> 6) & 7, nt = idx >> 9;
      int n = nt * 16 + (lane & 15);
      int k0 = kt * 32 + (lane >> 4) * 8;
      u16* o = wpf + idx * 8;
      for (int j = 0; j < 8; j++) o[j] = f2b(wp_in[n * 256 + k0 + j]);
    }
  }
}

// ---------------------------------------------------------------------------
// counting sort by length (bins 1..20). Output order within a bin is
// nondeterministic but per-word results are independent of grouping.
// ---------------------------------------------------------------------------
__global__ void sort_zero(int* __restrict__ bins) {
  if (threadIdx.x < 32) bins[threadIdx.x] = 0;
}
__global__ void sort_hist(const int* __restrict__ lens, int* __restrict__ bins) {
  __shared__ int hcnt[32];
  int tid = threadIdx.x;
  if (tid < 32) hcnt[tid] = 0;
  __syncthreads();
  int gid = blockIdx.x * 256 + tid;
  int l = lens[gid] & 31;
  atomicAdd(&hcnt[l], 1);
  __syncthreads();
  if (tid < 32 && hcnt[tid]) atomicAdd(&bins[tid], hcnt[tid]);
}
// also computes c0 = sum_c tanh(bp[c])*ctx[c] (pad-position score)
__global__ void sort_scan(const int* __restrict__ bins, int* __restrict__ offsw,
                          const float* __restrict__ bp,
                          const float* __restrict__ ctx,
                          float* __restrict__ c0out) {
  if (threadIdx.x == 0 && blockIdx.x == 0) {
    int off = 0;
    for (int l = 0; l < 32; l++) {
      offsw[l] = off;
      off += bins[l];
    }
    float c0 = 0.f;
    for (int c = 0; c < 128; c++) c0 += fast_tanh(bp[c]) * ctx[c];
    *c0out = c0;
  }
}
__global__ void sort_scat(const int* __restrict__ lens, int* __restrict__ offsw,
                          int* __restrict__ perm) {
  __shared__ int lcnt[32];
  __shared__ int lbase[32];
  int tid = threadIdx.x;
  if (tid < 32) lcnt[tid] = 0;
  __syncthreads();
  int gid = blockIdx.x * 256 + tid;
  int l = lens[gid] & 31;
  int lr = atomicAdd(&lcnt[l], 1);
  __syncthreads();
  if (tid < 32) lbase[tid] = lcnt[tid] ? atomicAdd(&offsw[tid], lcnt[tid]) : 0;
  __syncthreads();
  perm[lbase[l] + lr] = gid;
}

// ---------------------------------------------------------------------------
// gru: grid 2*(nw/16) x 256. bid parity = direction; 16 sorted words/block.
// Wave wv owns hid [wv*32,+32): n-tiles nt = cls*8 + wv*2 + j2 (6 per wave),
// B-fragments resident in VGPRs. h exchanged via 4 KiB LDS (A-frag layout).
// ---------------------------------------------------------------------------
__global__ __launch_bounds__(256, 2) void gru_kernel(
    const int* __restrict__ chars, const int* __restrict__ lens,
    const int* __restrict__ perm,
    const u16* __restrict__ xpb_f, const u16* __restrict__ xpb_b,
    const u16* __restrict__ whhf, const u16* __restrict__ whhb,
    const float* __restrict__ bhh_f, const float* __restrict__ bhh_b,
    u16* __restrict__ hf, u16* __restrict__ hb, int word_off) {
  const int bid = blockIdx.x;
  const int dir = bid & 1;
  const int wg = bid >> 1;
  const int tid = threadIdx.x;

  __shared__ int perm_s[16];
  __shared__ unsigned char lens_s[16];
  __shared__ unsigned char chars_s[320];  // [s][w] pre-remapped
  __shared__ u16 h_s[2048];               // [kt4][ln64][8] A-frag layout

  if (tid < 16) {
    int p = perm[word_off + wg * 16 + tid];
    perm_s[tid] = p;
    lens_s[tid] = (unsigned char)lens[p];
  }
  for (int i = tid; i < 1024; i += 256) ((uint32_t*)h_s)[i] = 0u;
  __syncthreads();

  for (int i = tid; i < 320; i += 256) {
    int w = i & 15, s = i >> 4;
    int L = lens_s[w];
    int t = dir ? ((s < L) ? (L - 1 - s) : s) : s;
    chars_s[s * 16 + w] = (unsigned char)chars[perm_s[w] * 20 + t];
  }

  const u16* xp = dir ? xpb_b : xpb_f;
  const u16* whh = dir ? whhb : whhf;
  const float* bhh = dir ? bhh_b : bhh_f;
  u16* hout = (dir ? hb : hf) + (size_t)wg * 16 * 2560;

  const int wv = tid >> 6, ln = tid & 63, col = ln & 15, grp = ln >> 4;

  // Whh B-fragments -> VGPRs (96 regs), once per block
  bf16x8 Bf[6][4];
#pragma unroll
  for (int n = 0; n < 6; n++) {
    int cls = n >> 1, j2 = n & 1;
    int nt = cls * 8 + wv * 2 + j2;
#pragma unroll
    for (int kt = 0; kt < 4; kt++)
      Bf[n][kt] = *(const bf16x8*)(whh + (((nt * 4 + kt) * 64 + ln) << 3));
  }

  float bh[6];
#pragma unroll
  for (int n = 0; n < 6; n++) {
    int cls = n >> 1, j2 = n & 1;
    bh[n] = bhh[cls * 128 + wv * 32 + j2 * 16 + col];
  }

  __syncthreads();  // chars_s + h_s zero complete

  int Lmax = 1;
  for (int i = 0; i < 16; i++) Lmax = max(Lmax, (int)lens_s[i]);

  // store-phase constants (thread -> (word, k16) of the 16x128 h tile)
  const int swd = tid >> 4;
  const int k16 = (tid & 15) << 3;
  const int skt = k16 >> 5;
  const int slan = swd | (((k16 >> 3) & 3) << 4);
  const int sL = lens_s[swd];

  float h[4][2];
#pragma unroll
  for (int r = 0; r < 4; r++) { h[r][0] = 0.f; h[r][1] = 0.f; }

  for (int s = 0; s < Lmax; s++) {
    // xp gathers (L2-resident table), consumed after MFMA -> latency hidden
    uint4 xq[4];
#pragma unroll
    for (int r = 0; r < 4; r++) {
      int c = chars_s[s * 16 + grp * 4 + r];
      xq[r] = *(const uint4*)(xp + (((c << 6) + (wv << 4) + col) << 3));
    }

    f32x4 acc[6];
#pragma unroll
    for (int n = 0; n < 6; n++) acc[n] = (f32x4){bh[n], bh[n], bh[n], bh[n]};
#pragma unroll
    for (int kt = 0; kt < 4; kt++) {
      bf16x8 Af = *(const bf16x8*)(h_s + ((kt * 64 + ln) << 3));
#pragma unroll
      for (int n = 0; n < 6; n++)
        acc[n] = __builtin_amdgcn_mfma_f32_16x16x32_bf16(Af, Bf[n][kt], acc[n], 0, 0, 0);
    }
    __syncthreads();  // all h_s reads (A-frags + prev store) done

    // gates + h update + h_s write (8 scalar b16 stores)
#pragma unroll
    for (int r = 0; r < 4; r++) {
      const u16* e = (const u16*)&xq[r];
#pragma unroll
      for (int j2 = 0; j2 < 2; j2++) {
        float rr = fast_sig(b2f(e[j2]) + acc[j2][r]);
        float zz = fast_sig(b2f(e[2 + j2]) + acc[2 + j2][r]);
        float nn = fast_tanh(b2f(e[4 + j2]) + rr * acc[4 + j2][r]);
        float hn = (1.f - zz) * nn + zz * h[r][j2];
        h[r][j2] = hn;
        int lane_a = (grp * 4 + r) | ((j2 * 2 + (col >> 3)) << 4);
        h_s[((wv * 64 + lane_a) << 3) + (col & 7)] = f2b(hn);
      }
    }
    __syncthreads();  // h_s(new) complete

    // store h row (only t < L; compact by sorted index)
    if (s < sL) {
      int tdst = dir ? (sL - 1 - s) : s;
      uint4 v = *(const uint4*)(h_s + ((skt * 64 + slan) << 3));
      *(uint4*)(hout + ((size_t)swd * 20 + tdst) * 128 + k16) = v;
    }
  }
}

// ---------------------------------------------------------------------------
// attn: grid nw/64 x 256. 64 sorted words/block, 4 threads/word.
// Register double-buffer prefetch; online softmax over valid t; pad mass
// (20-L)*e^{c0-mrun} added to the denominator (reference semantics).
// ---------------------------------------------------------------------------
__global__ __launch_bounds__(256, 2) void attn_kernel(
    const u16* __restrict__ hf, const u16* __restrict__ hb,
    const u16* __restrict__ wpf,
    const float* __restrict__ bp, const float* __restrict__ ctx,
    const int* __restrict__ perm, const int* __restrict__ lens,
    const float* __restrict__ c0p,
    float* __restrict__ out, int word_off) {
  const int blk = blockIdx.x;
  const int lw0 = blk * 64;

  __shared__ u16 ot_s[16384];      // 32 KiB: Out_t frag layout
  __shared__ float part_s[4][64];
  __shared__ int perm_s[64];
  __shared__ unsigned char lens_s[64];

  const int tid = threadIdx.x;
  const int wv = tid >> 6, ln = tid & 63, col = ln & 15, grp = ln >> 4;
  const int sw = tid >> 2;
  const int seg = tid & 3;

  if (tid < 64) {
    int p = perm[word_off + lw0 + tid];
    perm_s[tid] = p;
    lens_s[tid] = (unsigned char)lens[p];
  }
  __syncthreads();
  int Lmax = 1;
  for (int i = 0; i < 64; i++) Lmax = max(Lmax, (int)lens_s[i]);
  const int Lw = lens_s[sw];

  float bpv[2], ctxv[2];
#pragma unroll
  for (int n = 0; n < 2; n++) {
    int nt = wv + n * 4;
    bpv[n] = bp[nt * 16 + col];
    ctxv[n] = ctx[nt * 16 + col];
  }

  float facc[64];
#pragma unroll
  for (int i = 0; i < 64; i++) facc[i] = 0.f;
  float mrun = -3.0e38f, drun = 0.f;

  const u16* srcbase =
      ((seg < 2) ? hf : hb) + (size_t)(lw0 + sw) * 2560 + (seg & 1) * 64;

  uint4 vn[8];
#pragma unroll
  for (int q = 0; q < 8; q++) vn[q] = *(const uint4*)(srcbase + q * 8);

  for (int t = 0; t < Lmax; t++) {
    uint4 v[8];
#pragma unroll
    for (int q = 0; q < 8; q++) v[q] = vn[q];

    // stage Out_t into frag layout
#pragma unroll
    for (int q = 0; q < 8; q++) {
      int kt = seg * 2 + (q >> 2);
      int lane_a = (sw & 15) | ((q & 3) << 4);
      int m = sw >> 4;
      *(uint4*)(ot_s + (((m * 8 + kt) * 64 + lane_a) << 3)) = v[q];
    }
    // prefetch next t (hidden under MFMA/score)
    if (t + 1 < Lmax) {
      const u16* src = srcbase + (t + 1) * 128;
#pragma unroll
      for (int q = 0; q < 8; q++) vn[q] = *(const uint4*)(src + q * 8);
    }
    __syncthreads();

    // proj = Out_t @ Wp^T + bp (Wp frags from L2)
    f32x4 acc[2][4];
#pragma unroll
    for (int n = 0; n < 2; n++)
#pragma unroll
      for (int m = 0; m < 4; m++) acc[n][m] = (f32x4){bpv[n], bpv[n], bpv[n], bpv[n]};

#pragma unroll
    for (int kt = 0; kt < 8; kt++) {
      bf16x8 Af[4];
#pragma unroll
      for (int m = 0; m < 4; m++)
        Af[m] = *(const bf16x8*)(ot_s + (((m * 8 + kt) * 64 + ln) << 3));
#pragma unroll
      for (int n = 0; n < 2; n++) {
        int nt = wv + n * 4;
        bf16x8 Bf = *(const bf16x8*)(wpf + (((nt * 8 + kt) * 64 + ln) << 3));
#pragma unroll
        for (int m = 0; m < 4; m++)
          acc[n][m] = __builtin_amdgcn_mfma_f32_16x16x32_bf16(Af[m], Bf, acc[n][m], 0, 0, 0);
      }
    }

    // score partials
#pragma unroll
    for (int m = 0; m < 4; m++) {
#pragma unroll
      for (int r = 0; r < 4; r++) {
        float p = fast_tanh(acc[0][m][r]) * ctxv[0] +
                  fast_tanh(acc[1][m][r]) * ctxv[1];
        p += __shfl_xor(p, 1, 64);
        p += __shfl_xor(p, 2, 64);
        p += __shfl_xor(p, 4, 64);
        p += __shfl_xor(p, 8, 64);
        if (col == 0) part_s[wv][m * 16 + grp * 4 + r] = p;
      }
    }
    __syncthreads();

    float sc = part_s[0][sw] + part_s[1][sw] + part_s[2][sw] + part_s[3][sw];

    // online softmax update (valid t only; scale=1,e=0 for invalid anyway,
    // and skipping avoids 0*garbage from never-written pad rows)
    if (t < Lw) {
      float mnew = fmaxf(mrun, sc);
      float scale = EXP2F(LOG2E * (mrun - mnew));
      float e = EXP2F(LOG2E * (sc - mnew));
      drun = drun * scale + e;
      mrun = mnew;
#pragma unroll
      for (int q = 0; q < 8; q++) {
        const u16* pv = (const u16*)&v[q];
#pragma unroll
        for (int j = 0; j < 8; j++)
          facc[q * 8 + j] = facc[q * 8 + j] * scale + e * b2f(pv[j]);
      }
    }
  }

  // reference semantics: softmax over all 20 positions; pads have score c0
  // and zero data rows -> denominator-only mass (bounded: |c0|,|s|<=12.8).
  drun += (float)(20 - Lw) * EXP2F(LOG2E * (*c0p - mrun));

  float inv = RCPF(drun);
  float* dst = out + (size_t)perm_s[sw] * 256 + seg * 64;
#pragma unroll
  for (int i = 0; i < 64; i++) dst[i] = facc[i] * inv;
}

// ---------------------------------------------------------------------------
extern "C" void kernel_launch(void* const* d_in, const int* in_sizes, int n_in,
                              void* d_out, int out_size, void* d_ws, size_t ws_size,
                              hipStream_t stream) {
  const int* chars = (const int*)d_in[0];
  const int* lens = (const int*)d_in[1];
  const float* emb = (const float*)d_in[2];
  const float* wih_f = (const float*)d_in[3];
  const float* whh_f = (const float*)d_in[4];
  const float* bih_f = (const float*)d_in[5];
  const float* bhh_f = (const float*)d_in[6];
  const float* wih_b = (const float*)d_in[7];
  const float* whh_b = (const float*)d_in[8];
  const float* bih_b = (const float*)d_in[9];
  const float* bhh_b = (const float*)d_in[10];
  const float* wp = (const float*)d_in[11];
  const float* bp = (const float*)d_in[12];
  const float* ctx = (const float*)d_in[13];
  float* outp = (float*)d_out;

  uint8_t* ws = (uint8_t*)d_ws;
  u16* xpb_f = (u16*)(ws + 0);                // 128 KiB
  u16* xpb_b = (u16*)(ws + 131072);           // 128 KiB
  u16* whhf = (u16*)(ws + 262144);            // 96 KiB
  u16* whhb = (u16*)(ws + 360448);            // 96 KiB
  u16* wpf = (u16*)(ws + 458752);             // 64 KiB
  int* bins = (int*)(ws + 524288);            // 128 B
  int* offsw = (int*)(ws + 524416);           // 128 B
  float* c0p = (float*)(ws + 524544);         // 16 B
  int* permp = (int*)(ws + 524560);           // 128 KiB
  const size_t H_OFF = 786432;

  prep_kernel<<<576, 256, 0, stream>>>(emb, wih_f, bih_f, wih_b, bih_b, whh_f,
                                       whh_b, wp, xpb_f, xpb_b, whhf, whhb, wpf);
  sort_zero<<<1, 64, 0, stream>>>(bins);
  sort_hist<<<128, 256, 0, stream>>>(lens, bins);
  sort_scan<<<1, 64, 0, stream>>>(bins, offsw, bp, ctx, c0p);
  sort_scat<<<128, 256, 0, stream>>>(lens, offsw, permp);

  const size_t per_word = 20 * 128 * 2 * 2;  // hf+hb bytes per word
  size_t avail = (ws_size > H_OFF) ? (ws_size - H_OFF) : 0;
  int maxw = (int)(avail / per_word) & ~63;
  if (maxw > 32768) maxw = 32768;
  if (maxw < 64) maxw = 64;

  for (int done = 0; done < 32768;) {
    int nw = (32768 - done < maxw) ? (32768 - done) : maxw;
    u16* hfp = (u16*)(ws + H_OFF);
    u16* hbp = hfp + (size_t)nw * 2560;
    gru_kernel<<<(nw / 16) * 2, 256, 0, stream>>>(
        chars, lens, permp, xpb_f, xpb_b, whhf, whhb, bhh_f, bhh_b, hfp, hbp, done);
    attn_kernel<<<nw / 64, 256, 0, stream>>>(hfp, hbp, wpf, bp, ctx, permp,
                                             lens, c0p, outp, done);
    done += nw;
  }
}

// Round 5
// 269.703 us; speedup vs baseline: 3.0798x; 1.6331x over previous
//
#include <hip/hip_runtime.h>
#include <hip/hip_bf16.h>
#include <stdint.h>

// ---------------------------------------------------------------------------
// CharToWord v5: bidirectional char-GRU + attention pooling.
// v4 post-mortem: BOTH kernels were VGPR-capped by launch_bounds(...,2) to 128
// while needing ~175-190 regs -> scratch spills dominated (attn: MfmaUtil 2%,
// FETCH 32MB of spill traffic). v5 rule: occupancy via smaller state, never
// via a cap below need.
//  - gru: (256,1) uncapped (~190 regs, 2 waves/SIMD, zero spill); h_s double
//    buffer -> ONE barrier/step.
//  - attn: 16 threads/word (facc[16], ~85 regs) -> fits the 128 cap with
//    slack, 4 waves/SIMD, zero spill. 16 words/block.
//  - counting sort by length retained; pad softmax mass (20-L)*e^{c0} retained.
// ---------------------------------------------------------------------------

typedef unsigned short u16;
typedef float f32x4 __attribute__((ext_vector_type(4)));
typedef __bf16 bf16x8 __attribute__((ext_vector_type(8)));

#if __has_builtin(__builtin_amdgcn_exp2f)
#define EXP2F(x) __builtin_amdgcn_exp2f(x)
#else
#define EXP2F(x) exp2f(x)
#endif
#if __has_builtin(__builtin_amdgcn_rcpf)
#define RCPF(x) __builtin_amdgcn_rcpf(x)
#else
#define RCPF(x) (1.0f / (x))
#endif

#define LOG2E 1.4426950408889634f

__device__ __forceinline__ u16 f2b(float f) {
  uint32_t u = __builtin_bit_cast(uint32_t, f);
  u = u + 0x7FFFu + ((u >> 16) & 1u);
  return (u16)(u >> 16);
}
__device__ __forceinline__ float b2f(u16 s) {
  uint32_t u = ((uint32_t)s) << 16;
  return __builtin_bit_cast(float, u);
}
__device__ __forceinline__ float fast_sig(float x) {
  return RCPF(1.0f + EXP2F(-LOG2E * x));
}
__device__ __forceinline__ float fast_tanh(float x) {
  return 1.0f - 2.0f * RCPF(EXP2F(2.0f * LOG2E * x) + 1.0f);
}

// ---------------------------------------------------------------------------
// prep: grid 576 x 256
//  blocks [0,512)   : xp tables (bf16), layout [c][wv*16+col][8] (idx cls*2+j2)
//  blocks [512,560) : Whh frag bf16, chunks ((nt*4+kt)*64+lane)*8
//  blocks [560,576) : Wp frag bf16,  chunks ((nt*8+kt)*64+lane)*8
// ---------------------------------------------------------------------------
__global__ void prep_kernel(
    const float* __restrict__ emb,
    const float* __restrict__ wih_f, const float* __restrict__ bih_f,
    const float* __restrict__ wih_b, const float* __restrict__ bih_b,
    const float* __restrict__ whh_f_in, const float* __restrict__ whh_b_in,
    const float* __restrict__ wp_in,
    u16* __restrict__ xpb_f, u16* __restrict__ xpb_b,
    u16* __restrict__ whhf, u16* __restrict__ whhb, u16* __restrict__ wpf) {
  int gid = blockIdx.x * 256 + threadIdx.x;
  if (blockIdx.x < 512) {
    int d = gid >> 16;          // 65536 entries per direction
    int r = gid & 65535;
    int c = r >> 9;             // 512 per char
    int r2 = r & 511;
    int wc = r2 >> 3;           // wv*16 + col
    int i8 = r2 & 7;
    float v = 0.f;
    if (i8 < 6) {
      int cls = i8 >> 1, j2 = i8 & 1;
      int gate = cls * 128 + (wc >> 4) * 32 + j2 * 16 + (wc & 15);
      const float* wih = d ? wih_b : wih_f;
      const float* bih = d ? bih_b : bih_f;
      const float4* e4 = (const float4*)(emb + c * 64);
      const float4* w4 = (const float4*)(wih + gate * 64);
      float s = 0.f;
#pragma unroll
      for (int e = 0; e < 16; e++) {
        float4 a = e4[e], b = w4[e];
        s += a.x * b.x + a.y * b.y + a.z * b.z + a.w * b.w;
      }
      v = s + bih[gate];
    }
    (d ? xpb_b : xpb_f)[(c << 9) + r2] = f2b(v);
  } else if (blockIdx.x < 560) {
    int idx = gid - 512 * 256;  // 0..12287
    int d = (idx >= 6144) ? 1 : 0;
    int r = idx - d * 6144;
    int lane = r & 63, kt = (r >> 6) & 3, nt = r >> 8;
    int n = nt * 16 + (lane & 15);
    int k0 = kt * 32 + (lane >> 4) * 8;
    const float* w = d ? whh_b_in : whh_f_in;
    u16* o = (d ? whhb : whhf) + r * 8;
    for (int j = 0; j < 8; j++) o[j] = f2b(w[n * 128 + k0 + j]);
  } else {
    int idx = gid - 560 * 256;  // 0..4095
    if (idx < 4096) {
      int lane = idx & 63, kt = (idx >> 6) & 7, nt = idx >> 9;
      int n = nt * 16 + (lane & 15);
      int k0 = kt * 32 + (lane >> 4) * 8;
      u16* o = wpf + idx * 8;
      for (int j = 0; j < 8; j++) o[j] = f2b(wp_in[n * 256 + k0 + j]);
    }
  }
}

// ---------------------------------------------------------------------------
// counting sort by length (bins 1..20); c0 = pad-position attention score.
// ---------------------------------------------------------------------------
__global__ void sort_zero(int* __restrict__ bins) {
  if (threadIdx.x < 32) bins[threadIdx.x] = 0;
}
__global__ void sort_hist(const int* __restrict__ lens, int* __restrict__ bins) {
  __shared__ int hcnt[32];
  int tid = threadIdx.x;
  if (tid < 32) hcnt[tid] = 0;
  __syncthreads();
  int gid = blockIdx.x * 256 + tid;
  int l = lens[gid] & 31;
  atomicAdd(&hcnt[l], 1);
  __syncthreads();
  if (tid < 32 && hcnt[tid]) atomicAdd(&bins[tid], hcnt[tid]);
}
__global__ void sort_scan(const int* __restrict__ bins, int* __restrict__ offsw,
                          const float* __restrict__ bp,
                          const float* __restrict__ ctx,
                          float* __restrict__ c0out) {
  if (threadIdx.x == 0 && blockIdx.x == 0) {
    int off = 0;
    for (int l = 0; l < 32; l++) {
      offsw[l] = off;
      off += bins[l];
    }
    float c0 = 0.f;
    for (int c = 0; c < 128; c++) c0 += fast_tanh(bp[c]) * ctx[c];
    *c0out = c0;
  }
}
__global__ void sort_scat(const int* __restrict__ lens, int* __restrict__ offsw,
                          int* __restrict__ perm) {
  __shared__ int lcnt[32];
  __shared__ int lbase[32];
  int tid = threadIdx.x;
  if (tid < 32) lcnt[tid] = 0;
  __syncthreads();
  int gid = blockIdx.x * 256 + tid;
  int l = lens[gid] & 31;
  int lr = atomicAdd(&lcnt[l], 1);
  __syncthreads();
  if (tid < 32) lbase[tid] = lcnt[tid] ? atomicAdd(&offsw[tid], lcnt[tid]) : 0;
  __syncthreads();
  perm[lbase[l] + lr] = gid;
}

// ---------------------------------------------------------------------------
// gru: grid 2*(nw/16) x 256. bid parity = direction; 16 sorted words/block.
// Wave wv owns hid [wv*32,+32): n-tiles nt = cls*8 + wv*2 + j2 (6 per wave),
// B-fragments resident in VGPRs (uncapped regs). h_s double-buffered:
// one barrier per step.
// ---------------------------------------------------------------------------
__global__ __launch_bounds__(256, 1) void gru_kernel(
    const int* __restrict__ chars, const int* __restrict__ lens,
    const int* __restrict__ perm,
    const u16* __restrict__ xpb_f, const u16* __restrict__ xpb_b,
    const u16* __restrict__ whhf, const u16* __restrict__ whhb,
    const float* __restrict__ bhh_f, const float* __restrict__ bhh_b,
    u16* __restrict__ hf, u16* __restrict__ hb, int word_off) {
  const int bid = blockIdx.x;
  const int dir = bid & 1;
  const int wg = bid >> 1;
  const int tid = threadIdx.x;

  __shared__ int perm_s[16];
  __shared__ unsigned char lens_s[16];
  __shared__ unsigned char chars_s[320];  // [s][w] pre-remapped
  __shared__ u16 h_s[2][2048];            // double-buffered A-frag layout

  if (tid < 16) {
    int p = perm[word_off + wg * 16 + tid];
    perm_s[tid] = p;
    lens_s[tid] = (unsigned char)lens[p];
  }
  for (int i = tid; i < 1024; i += 256) ((uint32_t*)h_s[0])[i] = 0u;
  __syncthreads();

  for (int i = tid; i < 320; i += 256) {
    int w = i & 15, s = i >> 4;
    int L = lens_s[w];
    int t = dir ? ((s < L) ? (L - 1 - s) : s) : s;
    chars_s[s * 16 + w] = (unsigned char)chars[perm_s[w] * 20 + t];
  }

  const u16* xp = dir ? xpb_b : xpb_f;
  const u16* whh = dir ? whhb : whhf;
  const float* bhh = dir ? bhh_b : bhh_f;
  u16* hout = (dir ? hb : hf) + (size_t)wg * 16 * 2560;

  const int wv = tid >> 6, ln = tid & 63, col = ln & 15, grp = ln >> 4;

  // Whh B-fragments -> VGPRs (96 regs), once per block
  bf16x8 Bf[6][4];
#pragma unroll
  for (int n = 0; n < 6; n++) {
    int cls = n >> 1, j2 = n & 1;
    int nt = cls * 8 + wv * 2 + j2;
#pragma unroll
    for (int kt = 0; kt < 4; kt++)
      Bf[n][kt] = *(const bf16x8*)(whh + (((nt * 4 + kt) * 64 + ln) << 3));
  }

  float bh[6];
#pragma unroll
  for (int n = 0; n < 6; n++) {
    int cls = n >> 1, j2 = n & 1;
    bh[n] = bhh[cls * 128 + wv * 32 + j2 * 16 + col];
  }

  __syncthreads();  // chars_s ready

  int Lmax = 1;
  for (int i = 0; i < 16; i++) Lmax = max(Lmax, (int)lens_s[i]);

  // store-phase constants (thread -> (word, k16) of the 16x128 h tile)
  const int swd = tid >> 4;
  const int k16 = (tid & 15) << 3;
  const int skt = k16 >> 5;
  const int slan = swd | (((k16 >> 3) & 3) << 4);
  const int sL = lens_s[swd];

  float h[4][2];
#pragma unroll
  for (int r = 0; r < 4; r++) { h[r][0] = 0.f; h[r][1] = 0.f; }

  for (int s = 0; s < Lmax; s++) {
    const u16* hcur = h_s[s & 1];
    u16* hnxt = h_s[(s + 1) & 1];

    // xp gathers (L2-resident table)
    uint4 xq[4];
#pragma unroll
    for (int r = 0; r < 4; r++) {
      int c = chars_s[s * 16 + grp * 4 + r];
      xq[r] = *(const uint4*)(xp + (((c << 6) + (wv << 4) + col) << 3));
    }

    f32x4 acc[6];
#pragma unroll
    for (int n = 0; n < 6; n++) acc[n] = (f32x4){bh[n], bh[n], bh[n], bh[n]};
#pragma unroll
    for (int kt = 0; kt < 4; kt++) {
      bf16x8 Af = *(const bf16x8*)(hcur + ((kt * 64 + ln) << 3));
#pragma unroll
      for (int n = 0; n < 6; n++)
        acc[n] = __builtin_amdgcn_mfma_f32_16x16x32_bf16(Af, Bf[n][kt], acc[n], 0, 0, 0);
    }

    // gates + h update -> write OTHER buffer (no barrier needed before)
#pragma unroll
    for (int r = 0; r < 4; r++) {
      const u16* e = (const u16*)&xq[r];
#pragma unroll
      for (int j2 = 0; j2 < 2; j2++) {
        float rr = fast_sig(b2f(e[j2]) + acc[j2][r]);
        float zz = fast_sig(b2f(e[2 + j2]) + acc[2 + j2][r]);
        float nn = fast_tanh(b2f(e[4 + j2]) + rr * acc[4 + j2][r]);
        float hn = (1.f - zz) * nn + zz * h[r][j2];
        h[r][j2] = hn;
        int lane_a = (grp * 4 + r) | ((j2 * 2 + (col >> 3)) << 4);
        hnxt[((wv * 64 + lane_a) << 3) + (col & 7)] = f2b(hn);
      }
    }
    __syncthreads();  // hnxt complete; hcur reads all done

    // store h row (only t < L; compact by sorted index)
    if (s < sL) {
      int tdst = dir ? (sL - 1 - s) : s;
      uint4 v = *(const uint4*)(hnxt + ((skt * 64 + slan) << 3));
      *(uint4*)(hout + ((size_t)swd * 20 + tdst) * 128 + k16) = v;
    }
  }
}

// ---------------------------------------------------------------------------
// attn: grid nw/16 x 256. 16 sorted words/block, 16 threads/word (facc[16]).
// ~85 regs/thread -> no spill under the 128 cap, 4 waves/SIMD.
// Online softmax over valid t + pad mass (20-L)*e^{c0-mrun}.
// ---------------------------------------------------------------------------
__global__ __launch_bounds__(256, 2) void attn_kernel(
    const u16* __restrict__ hf, const u16* __restrict__ hb,
    const u16* __restrict__ wpf,
    const float* __restrict__ bp, const float* __restrict__ ctx,
    const int* __restrict__ perm, const int* __restrict__ lens,
    const float* __restrict__ c0p,
    float* __restrict__ out, int word_off) {
  const int blk = blockIdx.x;
  const int lw0 = blk * 16;

  __shared__ u16 ot_s[4096];       // 8 KiB: Out_t frag layout (16x256)
  __shared__ float part_s[4][16];
  __shared__ int perm_s[16];
  __shared__ unsigned char lens_s[16];

  const int tid = threadIdx.x;
  const int wv = tid >> 6, ln = tid & 63, col = ln & 15, grp = ln >> 4;
  const int sw = tid >> 4;   // this thread's word (16 threads per word)
  const int seg = tid & 15;  // 16-dim segment of the 256-dim output

  if (tid < 16) {
    int p = perm[word_off + lw0 + tid];
    perm_s[tid] = p;
    lens_s[tid] = (unsigned char)lens[p];
  }
  __syncthreads();
  int Lmax = 1;
#pragma unroll
  for (int i = 0; i < 16; i++) Lmax = max(Lmax, (int)lens_s[i]);
  const int Lw = lens_s[sw];

  float bpv[2], ctxv[2];
#pragma unroll
  for (int n = 0; n < 2; n++) {
    int nt = wv + n * 4;
    bpv[n] = bp[nt * 16 + col];
    ctxv[n] = ctx[nt * 16 + col];
  }

  float facc[16];
#pragma unroll
  for (int i = 0; i < 16; i++) facc[i] = 0.f;
  float mrun = -3.0e38f, drun = 0.f;

  // seg 0..7 -> hf dims [seg*16, +16); seg 8..15 -> hb dims [(seg-8)*16, +16)
  const u16* srcbase =
      ((seg < 8) ? hf : hb) + (size_t)(lw0 + sw) * 2560 + (seg & 7) * 16;

  uint4 vn[2];
#pragma unroll
  for (int q = 0; q < 2; q++) vn[q] = *(const uint4*)(srcbase + q * 8);

  for (int t = 0; t < Lmax; t++) {
    uint4 v[2];
    v[0] = vn[0];
    v[1] = vn[1];

    // stage Out_t into frag layout: k = seg*16 + q*8
#pragma unroll
    for (int q = 0; q < 2; q++) {
      int idx = seg * 2 + q;           // k>>3, 0..31
      int kt = idx >> 2;               // k>>5
      int lane_a = sw | ((idx & 3) << 4);
      *(uint4*)(ot_s + ((kt * 64 + lane_a) << 3)) = v[q];
    }
    // prefetch next t (hidden under MFMA/score)
    if (t + 1 < Lmax) {
      const u16* src = srcbase + (t + 1) * 128;
#pragma unroll
      for (int q = 0; q < 2; q++) vn[q] = *(const uint4*)(src + q * 8);
    }
    __syncthreads();

    // proj = Out_t @ Wp^T + bp (Wp frags from L2)
    f32x4 acc[2];
#pragma unroll
    for (int n = 0; n < 2; n++) acc[n] = (f32x4){bpv[n], bpv[n], bpv[n], bpv[n]};

#pragma unroll
    for (int kt = 0; kt < 8; kt++) {
      bf16x8 Af = *(const bf16x8*)(ot_s + ((kt * 64 + ln) << 3));
#pragma unroll
      for (int n = 0; n < 2; n++) {
        int nt = wv + n * 4;
        bf16x8 Bf = *(const bf16x8*)(wpf + (((nt * 8 + kt) * 64 + ln) << 3));
        acc[n] = __builtin_amdgcn_mfma_f32_16x16x32_bf16(Af, Bf, acc[n], 0, 0, 0);
      }
    }

    // score partials: sum over proj dims (cols), words live in (grp*4+r)
#pragma unroll
    for (int r = 0; r < 4; r++) {
      float p = fast_tanh(acc[0][r]) * ctxv[0] + fast_tanh(acc[1][r]) * ctxv[1];
      p += __shfl_xor(p, 1, 64);
      p += __shfl_xor(p, 2, 64);
      p += __shfl_xor(p, 4, 64);
      p += __shfl_xor(p, 8, 64);
      if (col == 0) part_s[wv][grp * 4 + r] = p;
    }
    __syncthreads();

    float sc = part_s[0][sw] + part_s[1][sw] + part_s[2][sw] + part_s[3][sw];

    if (t < Lw) {
      float mnew = fmaxf(mrun, sc);
      float scale = EXP2F(LOG2E * (mrun - mnew));
      float e = EXP2F(LOG2E * (sc - mnew));
      drun = drun * scale + e;
      mrun = mnew;
#pragma unroll
      for (int q = 0; q < 2; q++) {
        const u16* pv = (const u16*)&v[q];
#pragma unroll
        for (int j = 0; j < 8; j++)
          facc[q * 8 + j] = facc[q * 8 + j] * scale + e * b2f(pv[j]);
      }
    }
  }

  // softmax runs over all 20 positions in the reference; pad rows are zero
  // with constant score c0 -> denominator-only mass.
  drun += (float)(20 - Lw) * EXP2F(LOG2E * (*c0p - mrun));

  float inv = RCPF(drun);
  float* dst = out + (size_t)perm_s[sw] * 256 + seg * 16;
#pragma unroll
  for (int i = 0; i < 4; i++) {
    float4 o = make_float4(facc[i * 4] * inv, facc[i * 4 + 1] * inv,
                           facc[i * 4 + 2] * inv, facc[i * 4 + 3] * inv);
    *(float4*)(dst + i * 4) = o;
  }
}

// ---------------------------------------------------------------------------
extern "C" void kernel_launch(void* const* d_in, const int* in_sizes, int n_in,
                              void* d_out, int out_size, void* d_ws, size_t ws_size,
                              hipStream_t stream) {
  const int* chars = (const int*)d_in[0];
  const int* lens = (const int*)d_in[1];
  const float* emb = (const float*)d_in[2];
  const float* wih_f = (const float*)d_in[3];
  const float* whh_f = (const float*)d_in[4];
  const float* bih_f = (const float*)d_in[5];
  const float* bhh_f = (const float*)d_in[6];
  const float* wih_b = (const float*)d_in[7];
  const float* whh_b = (const float*)d_in[8];
  const float* bih_b = (const float*)d_in[9];
  const float* bhh_b = (const float*)d_in[10];
  const float* wp = (const float*)d_in[11];
  const float* bp = (const float*)d_in[12];
  const float* ctx = (const float*)d_in[13];
  float* outp = (float*)d_out;

  uint8_t* ws = (uint8_t*)d_ws;
  u16* xpb_f = (u16*)(ws + 0);                // 128 KiB
  u16* xpb_b = (u16*)(ws + 131072);           // 128 KiB
  u16* whhf = (u16*)(ws + 262144);            // 96 KiB
  u16* whhb = (u16*)(ws + 360448);            // 96 KiB
  u16* wpf = (u16*)(ws + 458752);             // 64 KiB
  int* bins = (int*)(ws + 524288);            // 128 B
  int* offsw = (int*)(ws + 524416);           // 128 B
  float* c0p = (float*)(ws + 524544);         // 16 B
  int* permp = (int*)(ws + 524560);           // 128 KiB
  const size_t H_OFF = 786432;

  prep_kernel<<<576, 256, 0, stream>>>(emb, wih_f, bih_f, wih_b, bih_b, whh_f,
                                       whh_b, wp, xpb_f, xpb_b, whhf, whhb, wpf);
  sort_zero<<<1, 64, 0, stream>>>(bins);
  sort_hist<<<128, 256, 0, stream>>>(lens, bins);
  sort_scan<<<1, 64, 0, stream>>>(bins, offsw, bp, ctx, c0p);
  sort_scat<<<128, 256, 0, stream>>>(lens, offsw, permp);

  const size_t per_word = 20 * 128 * 2 * 2;  // hf+hb bytes per word
  size_t avail = (ws_size > H_OFF) ? (ws_size - H_OFF) : 0;
  int maxw = (int)(avail / per_word) & ~63;
  if (maxw > 32768) maxw = 32768;
  if (maxw < 64) maxw = 64;

  for (int done = 0; done < 32768;) {
    int nw = (32768 - done < maxw) ? (32768 - done) : maxw;
    u16* hfp = (u16*)(ws + H_OFF);
    u16* hbp = hfp + (size_t)nw * 2560;
    gru_kernel<<<(nw / 16) * 2, 256, 0, stream>>>(
        chars, lens, permp, xpb_f, xpb_b, whhf, whhb, bhh_f, bhh_b, hfp, hbp, done);
    attn_kernel<<<nw / 16, 256, 0, stream>>>(hfp, hbp, wpf, bp, ctx, permp,
                                             lens, c0p, outp, done);
    done += nw;
  }
}

// Round 6
// 262.821 us; speedup vs baseline: 3.1604x; 1.0262x over previous
//
#include <hip/hip_runtime.h>
#include <hip/hip_bf16.h>
#include <stdint.h>

// ---------------------------------------------------------------------------
// CharToWord v6: bidirectional char-GRU + attention pooling.
// v5 post-mortem: gru "VGPR=108" was arch-VGPRs only; Bf[6][4]+acc in the
// unified VGPR/AGPR file pushed true usage to ~230 -> 2 waves/SIMD (18.6% occ),
// and each wave issued ~550cy of gate VALU per step.
// v6: gru = 512 thr / 8 waves; wave owns (hid-group, j2-half) -> 3 n-tiles
// (Bf 48 regs), 4 gate-elems/thread (half the transcendentals per wave).
// ~115 regs -> launch_bounds(512,4) cap 128 is SLACK (v2/v4 rule), 2 blk/CU.
// xp table repacked per-j2 (uint2/thread), xq prefetch s+1, LPT block order.
// ---------------------------------------------------------------------------

typedef unsigned short u16;
typedef float f32x4 __attribute__((ext_vector_type(4)));
typedef __bf16 bf16x8 __attribute__((ext_vector_type(8)));

#if __has_builtin(__builtin_amdgcn_exp2f)
#define EXP2F(x) __builtin_amdgcn_exp2f(x)
#else
#define EXP2F(x) exp2f(x)
#endif
#if __has_builtin(__builtin_amdgcn_rcpf)
#define RCPF(x) __builtin_amdgcn_rcpf(x)
#else
#define RCPF(x) (1.0f / (x))
#endif

#define LOG2E 1.4426950408889634f

__device__ __forceinline__ u16 f2b(float f) {
  uint32_t u = __builtin_bit_cast(uint32_t, f);
  u = u + 0x7FFFu + ((u >> 16) & 1u);
  return (u16)(u >> 16);
}
__device__ __forceinline__ float b2f(u16 s) {
  uint32_t u = ((uint32_t)s) << 16;
  return __builtin_bit_cast(float, u);
}
__device__ __forceinline__ float fast_sig(float x) {
  return RCPF(1.0f + EXP2F(-LOG2E * x));
}
__device__ __forceinline__ float fast_tanh(float x) {
  return 1.0f - 2.0f * RCPF(EXP2F(2.0f * LOG2E * x) + 1.0f);
}

// ---------------------------------------------------------------------------
// prep: grid 1088 x 256
//  blocks [0,1024)    : xp tables (bf16), idx ((c*2+j2)*128 + w16)*4 + slot,
//                       slot = gate class (r,z,n, pad); w16 = hg*16+col
//  blocks [1024,1072) : Whh frag bf16, chunks ((nt*4+kt)*64+lane)*8
//  blocks [1072,1088) : Wp frag bf16,  chunks ((nt*8+kt)*64+lane)*8
// ---------------------------------------------------------------------------
__global__ void prep_kernel(
    const float* __restrict__ emb,
    const float* __restrict__ wih_f, const float* __restrict__ bih_f,
    const float* __restrict__ wih_b, const float* __restrict__ bih_b,
    const float* __restrict__ whh_f_in, const float* __restrict__ whh_b_in,
    const float* __restrict__ wp_in,
    u16* __restrict__ xpj_f, u16* __restrict__ xpj_b,
    u16* __restrict__ whhf, u16* __restrict__ whhb, u16* __restrict__ wpf) {
  int gid = blockIdx.x * 256 + threadIdx.x;
  if (blockIdx.x < 1024) {
    int d = gid >> 17;          // 131072 entries per direction
    int r = gid & 131071;
    int c = r >> 10;            // 1024 per char
    int r2 = r & 1023;
    int j2 = r2 >> 9;
    int r3 = r2 & 511;
    int w16 = r3 >> 2;          // hg*16 + col
    int slot = r3 & 3;
    float v = 0.f;
    if (slot < 3) {
      int gate = slot * 128 + (w16 >> 4) * 32 + j2 * 16 + (w16 & 15);
      const float* wih = d ? wih_b : wih_f;
      const float* bih = d ? bih_b : bih_f;
      const float4* e4 = (const float4*)(emb + c * 64);
      const float4* w4 = (const float4*)(wih + gate * 64);
      float s = 0.f;
#pragma unroll
      for (int e = 0; e < 16; e++) {
        float4 a = e4[e], b = w4[e];
        s += a.x * b.x + a.y * b.y + a.z * b.z + a.w * b.w;
      }
      v = s + bih[gate];
    }
    (d ? xpj_b : xpj_f)[r] = f2b(v);
  } else if (blockIdx.x < 1072) {
    int idx = gid - 1024 * 256;  // 0..12287
    int d = (idx >= 6144) ? 1 : 0;
    int r = idx - d * 6144;
    int lane = r & 63, kt = (r >> 6) & 3, nt = r >> 8;
    int n = nt * 16 + (lane & 15);
    int k0 = kt * 32 + (lane >> 4) * 8;
    const float* w = d ? whh_b_in : whh_f_in;
    u16* o = (d ? whhb : whhf) + r * 8;
    for (int j = 0; j < 8; j++) o[j] = f2b(w[n * 128 + k0 + j]);
  } else {
    int idx = gid - 1072 * 256;  // 0..4095
    if (idx < 4096) {
      int lane = idx & 63, kt = (idx >> 6) & 7, nt = idx >> 9;
      int n = nt * 16 + (lane & 15);
      int k0 = kt * 32 + (lane >> 4) * 8;
      u16* o = wpf + idx * 8;
      for (int j = 0; j < 8; j++) o[j] = f2b(wp_in[n * 256 + k0 + j]);
    }
  }
}

// ---------------------------------------------------------------------------
// counting sort by length (bins 1..20); c0 = pad-position attention score.
// ---------------------------------------------------------------------------
__global__ void sort_zero(int* __restrict__ bins) {
  if (threadIdx.x < 32) bins[threadIdx.x] = 0;
}
__global__ void sort_hist(const int* __restrict__ lens, int* __restrict__ bins) {
  __shared__ int hcnt[32];
  int tid = threadIdx.x;
  if (tid < 32) hcnt[tid] = 0;
  __syncthreads();
  int gid = blockIdx.x * 256 + tid;
  int l = lens[gid] & 31;
  atomicAdd(&hcnt[l], 1);
  __syncthreads();
  if (tid < 32 && hcnt[tid]) atomicAdd(&bins[tid], hcnt[tid]);
}
__global__ void sort_scan(const int* __restrict__ bins, int* __restrict__ offsw,
                          const float* __restrict__ bp,
                          const float* __restrict__ ctx,
                          float* __restrict__ c0out) {
  if (threadIdx.x == 0 && blockIdx.x == 0) {
    int off = 0;
    for (int l = 0; l < 32; l++) {
      offsw[l] = off;
      off += bins[l];
    }
    float c0 = 0.f;
    for (int c = 0; c < 128; c++) c0 += fast_tanh(bp[c]) * ctx[c];
    *c0out = c0;
  }
}
__global__ void sort_scat(const int* __restrict__ lens, int* __restrict__ offsw,
                          int* __restrict__ perm) {
  __shared__ int lcnt[32];
  __shared__ int lbase[32];
  int tid = threadIdx.x;
  if (tid < 32) lcnt[tid] = 0;
  __syncthreads();
  int gid = blockIdx.x * 256 + tid;
  int l = lens[gid] & 31;
  int lr = atomicAdd(&lcnt[l], 1);
  __syncthreads();
  if (tid < 32) lbase[tid] = lcnt[tid] ? atomicAdd(&offsw[tid], lcnt[tid]) : 0;
  __syncthreads();
  perm[lbase[l] + lr] = gid;
}

// ---------------------------------------------------------------------------
// gru: grid 2*nbd x 512. bid parity = direction; 16 sorted words/block.
// 8 waves: wave wv -> (hg = wv>>1, j2 = wv&1), 3 n-tiles nt = cls*8+hg*2+j2.
// Bf 48 regs/thread; 4 gate-elems/thread; h_s double-buffer, 1 barrier/step.
// LPT: wg reversed so longest blocks launch first.
// ---------------------------------------------------------------------------
__global__ __launch_bounds__(512, 4) void gru_kernel(
    const int* __restrict__ chars, const int* __restrict__ lens,
    const int* __restrict__ perm,
    const u16* __restrict__ xpj_f, const u16* __restrict__ xpj_b,
    const u16* __restrict__ whhf, const u16* __restrict__ whhb,
    const float* __restrict__ bhh_f, const float* __restrict__ bhh_b,
    u16* __restrict__ hf, u16* __restrict__ hb, int word_off, int nbd) {
  const int bid = blockIdx.x;
  const int dir = bid & 1;
  const int wg = nbd - 1 - (bid >> 1);  // longest-first (perm ascending)
  const int tid = threadIdx.x;

  __shared__ int perm_s[16];
  __shared__ unsigned char lens_s[16];
  __shared__ unsigned char chars_s[320];  // [s][w] pre-remapped
  __shared__ u16 h_s[2][2048];            // double-buffered A-frag layout

  if (tid < 16) {
    int p = perm[word_off + wg * 16 + tid];
    perm_s[tid] = p;
    lens_s[tid] = (unsigned char)lens[p];
  }
  for (int i = tid; i < 1024; i += 512) ((uint32_t*)h_s[0])[i] = 0u;
  __syncthreads();

  for (int i = tid; i < 320; i += 512) {
    int w = i & 15, s = i >> 4;
    int L = lens_s[w];
    int t = dir ? ((s < L) ? (L - 1 - s) : s) : s;
    chars_s[s * 16 + w] = (unsigned char)chars[perm_s[w] * 20 + t];
  }

  const u16* xp = dir ? xpj_b : xpj_f;
  const u16* whh = dir ? whhb : whhf;
  const float* bhh = dir ? bhh_b : bhh_f;
  u16* hout = (dir ? hb : hf) + (size_t)wg * 16 * 2560;

  const int wv = tid >> 6, ln = tid & 63, col = ln & 15, grp = ln >> 4;
  const int j2 = wv & 1, hg = wv >> 1;

  // Whh B-fragments -> 48 VGPRs, once per block
  bf16x8 Bf[3][4];
#pragma unroll
  for (int cls = 0; cls < 3; cls++) {
    int nt = cls * 8 + hg * 2 + j2;
#pragma unroll
    for (int kt = 0; kt < 4; kt++)
      Bf[cls][kt] = *(const bf16x8*)(whh + (((nt * 4 + kt) * 64 + ln) << 3));
  }

  float bh[3];
#pragma unroll
  for (int cls = 0; cls < 3; cls++)
    bh[cls] = bhh[cls * 128 + hg * 32 + j2 * 16 + col];

  __syncthreads();  // chars_s + h_s zero ready

  const int Lmax = lens_s[15];  // sorted ascending within block

  // store-phase constants: thread -> (word, 4-dim slice) of 16x128 h tile
  const int swd = tid >> 5;
  const int k4 = (tid & 31) << 2;
  const int skt = k4 >> 5;
  const int slan = swd | (((k4 >> 3) & 3) << 4);
  const int sslot = k4 & 7;
  const int sL = lens_s[swd];

  float h[4] = {0.f, 0.f, 0.f, 0.f};

  // prefetch xq for s=0 (uint2: gate slots r,z,n)
  uint2 xq[4];
#pragma unroll
  for (int r = 0; r < 4; r++) {
    int c = chars_s[grp * 4 + r];
    xq[r] = *(const uint2*)(xp + ((((c << 1) + j2) << 7) + (hg << 4) + col) * 4);
  }

  for (int s = 0; s < Lmax; s++) {
    const u16* hcur = h_s[s & 1];
    u16* hnxt = h_s[(s + 1) & 1];

    uint2 xc[4];
#pragma unroll
    for (int r = 0; r < 4; r++) xc[r] = xq[r];
    if (s + 1 < Lmax) {
#pragma unroll
      for (int r = 0; r < 4; r++) {
        int c = chars_s[(s + 1) * 16 + grp * 4 + r];
        xq[r] =
            *(const uint2*)(xp + ((((c << 1) + j2) << 7) + (hg << 4) + col) * 4);
      }
    }

    f32x4 acc[3];
#pragma unroll
    for (int cls = 0; cls < 3; cls++)
      acc[cls] = (f32x4){bh[cls], bh[cls], bh[cls], bh[cls]};
#pragma unroll
    for (int kt = 0; kt < 4; kt++) {
      bf16x8 Af = *(const bf16x8*)(hcur + ((kt * 64 + ln) << 3));
#pragma unroll
      for (int cls = 0; cls < 3; cls++)
        acc[cls] =
            __builtin_amdgcn_mfma_f32_16x16x32_bf16(Af, Bf[cls][kt], acc[cls], 0, 0, 0);
    }

    // gates (4 elems/thread) + write to OTHER buffer
#pragma unroll
    for (int r = 0; r < 4; r++) {
      const u16* e = (const u16*)&xc[r];
      float rr = fast_sig(b2f(e[0]) + acc[0][r]);
      float zz = fast_sig(b2f(e[1]) + acc[1][r]);
      float nn = fast_tanh(b2f(e[2]) + rr * acc[2][r]);
      float hn = (1.f - zz) * nn + zz * h[r];
      h[r] = hn;
      int lane_a = (grp * 4 + r) | ((j2 * 2 + (col >> 3)) << 4);
      hnxt[((hg * 64 + lane_a) << 3) + (col & 7)] = f2b(hn);
    }
    __syncthreads();  // hnxt complete; hcur reads done

    // store h row (only t < L), 8B/thread, coalesced
    if (s < sL) {
      int tdst = dir ? (sL - 1 - s) : s;
      uint2 v = *(const uint2*)(hnxt + ((skt * 64 + slan) << 3) + sslot);
      *(uint2*)(hout + ((size_t)swd * 20 + tdst) * 128 + k4) = v;
    }
  }
}

// ---------------------------------------------------------------------------
// attn: grid nbA x 256. 16 sorted words/block, 16 threads/word (facc[16]).
// Online softmax over valid t + pad mass (20-L)*e^{c0-mrun}. LPT order.
// ---------------------------------------------------------------------------
__global__ __launch_bounds__(256, 2) void attn_kernel(
    const u16* __restrict__ hf, const u16* __restrict__ hb,
    const u16* __restrict__ wpf,
    const float* __restrict__ bp, const float* __restrict__ ctx,
    const int* __restrict__ perm, const int* __restrict__ lens,
    const float* __restrict__ c0p,
    float* __restrict__ out, int word_off) {
  const int blk = gridDim.x - 1 - blockIdx.x;  // longest-first
  const int lw0 = blk * 16;

  __shared__ u16 ot_s[4096];       // 8 KiB: Out_t frag layout (16x256)
  __shared__ float part_s[4][16];
  __shared__ int perm_s[16];
  __shared__ unsigned char lens_s[16];

  const int tid = threadIdx.x;
  const int wv = tid >> 6, ln = tid & 63, col = ln & 15, grp = ln >> 4;
  const int sw = tid >> 4;   // this thread's word (16 threads per word)
  const int seg = tid & 15;  // 16-dim segment of the 256-dim output

  if (tid < 16) {
    int p = perm[word_off + lw0 + tid];
    perm_s[tid] = p;
    lens_s[tid] = (unsigned char)lens[p];
  }
  __syncthreads();
  const int Lmax = lens_s[15];  // sorted ascending within block
  const int Lw = lens_s[sw];

  float bpv[2], ctxv[2];
#pragma unroll
  for (int n = 0; n < 2; n++) {
    int nt = wv + n * 4;
    bpv[n] = bp[nt * 16 + col];
    ctxv[n] = ctx[nt * 16 + col];
  }

  float facc[16];
#pragma unroll
  for (int i = 0; i < 16; i++) facc[i] = 0.f;
  float mrun = -3.0e38f, drun = 0.f;

  // seg 0..7 -> hf dims [seg*16,+16); seg 8..15 -> hb dims [(seg-8)*16,+16)
  const u16* srcbase =
      ((seg < 8) ? hf : hb) + (size_t)(lw0 + sw) * 2560 + (seg & 7) * 16;

  uint4 vn[2];
#pragma unroll
  for (int q = 0; q < 2; q++) vn[q] = *(const uint4*)(srcbase + q * 8);

  for (int t = 0; t < Lmax; t++) {
    uint4 v[2];
    v[0] = vn[0];
    v[1] = vn[1];

    // stage Out_t into frag layout: k = seg*16 + q*8
#pragma unroll
    for (int q = 0; q < 2; q++) {
      int idx = seg * 2 + q;           // k>>3, 0..31
      int kt = idx >> 2;               // k>>5
      int lane_a = sw | ((idx & 3) << 4);
      *(uint4*)(ot_s + ((kt * 64 + lane_a) << 3)) = v[q];
    }
    // prefetch next t (hidden under MFMA/score)
    if (t + 1 < Lmax) {
      const u16* src = srcbase + (t + 1) * 128;
#pragma unroll
      for (int q = 0; q < 2; q++) vn[q] = *(const uint4*)(src + q * 8);
    }
    __syncthreads();

    // proj = Out_t @ Wp^T + bp (Wp frags from L2)
    f32x4 acc[2];
#pragma unroll
    for (int n = 0; n < 2; n++) acc[n] = (f32x4){bpv[n], bpv[n], bpv[n], bpv[n]};

#pragma unroll
    for (int kt = 0; kt < 8; kt++) {
      bf16x8 Af = *(const bf16x8*)(ot_s + ((kt * 64 + ln) << 3));
#pragma unroll
      for (int n = 0; n < 2; n++) {
        int nt = wv + n * 4;
        bf16x8 Bf = *(const bf16x8*)(wpf + (((nt * 8 + kt) * 64 + ln) << 3));
        acc[n] = __builtin_amdgcn_mfma_f32_16x16x32_bf16(Af, Bf, acc[n], 0, 0, 0);
      }
    }

    // score partials: tanh(proj)*ctx summed over cols; words at (grp*4+r)
#pragma unroll
    for (int r = 0; r < 4; r++) {
      float p = fast_tanh(acc[0][r]) * ctxv[0] + fast_tanh(acc[1][r]) * ctxv[1];
      p += __shfl_xor(p, 1, 64);
      p += __shfl_xor(p, 2, 64);
      p += __shfl_xor(p, 4, 64);
      p += __shfl_xor(p, 8, 64);
      if (col == 0) part_s[wv][grp * 4 + r] = p;
    }
    __syncthreads();

    float sc = part_s[0][sw] + part_s[1][sw] + part_s[2][sw] + part_s[3][sw];

    if (t < Lw) {
      float mnew = fmaxf(mrun, sc);
      float scale = EXP2F(LOG2E * (mrun - mnew));
      float e = EXP2F(LOG2E * (sc - mnew));
      drun = drun * scale + e;
      mrun = mnew;
#pragma unroll
      for (int q = 0; q < 2; q++) {
        const u16* pv = (const u16*)&v[q];
#pragma unroll
        for (int j = 0; j < 8; j++)
          facc[q * 8 + j] = facc[q * 8 + j] * scale + e * b2f(pv[j]);
      }
    }
  }

  // reference semantics: softmax over all 20 positions; pad rows are zero
  // with constant score c0 -> denominator-only mass.
  drun += (float)(20 - Lw) * EXP2F(LOG2E * (*c0p - mrun));

  float inv = RCPF(drun);
  float* dst = out + (size_t)perm_s[sw] * 256 + seg * 16;
#pragma unroll
  for (int i = 0; i < 4; i++) {
    float4 o = make_float4(facc[i * 4] * inv, facc[i * 4 + 1] * inv,
                           facc[i * 4 + 2] * inv, facc[i * 4 + 3] * inv);
    *(float4*)(dst + i * 4) = o;
  }
}

// ---------------------------------------------------------------------------
extern "C" void kernel_launch(void* const* d_in, const int* in_sizes, int n_in,
                              void* d_out, int out_size, void* d_ws, size_t ws_size,
                              hipStream_t stream) {
  const int* chars = (const int*)d_in[0];
  const int* lens = (const int*)d_in[1];
  const float* emb = (const float*)d_in[2];
  const float* wih_f = (const float*)d_in[3];
  const float* whh_f = (const float*)d_in[4];
  const float* bih_f = (const float*)d_in[5];
  const float* bhh_f = (const float*)d_in[6];
  const float* wih_b = (const float*)d_in[7];
  const float* whh_b = (const float*)d_in[8];
  const float* bih_b = (const float*)d_in[9];
  const float* bhh_b = (const float*)d_in[10];
  const float* wp = (const float*)d_in[11];
  const float* bp = (const float*)d_in[12];
  const float* ctx = (const float*)d_in[13];
  float* outp = (float*)d_out;

  uint8_t* ws = (uint8_t*)d_ws;
  u16* xpj_f = (u16*)(ws + 0);                // 256 KiB
  u16* xpj_b = (u16*)(ws + 262144);           // 256 KiB
  u16* whhf = (u16*)(ws + 524288);            // 96 KiB
  u16* whhb = (u16*)(ws + 622592);            // 96 KiB
  u16* wpf = (u16*)(ws + 720896);             // 64 KiB
  int* bins = (int*)(ws + 786432);            // 128 B
  int* offsw = (int*)(ws + 786560);           // 128 B
  float* c0p = (float*)(ws + 786688);         // 64 B
  int* permp = (int*)(ws + 786752);           // 128 KiB
  const size_t H_OFF = 1048576;

  prep_kernel<<<1088, 256, 0, stream>>>(emb, wih_f, bih_f, wih_b, bih_b, whh_f,
                                        whh_b, wp, xpj_f, xpj_b, whhf, whhb, wpf);
  sort_zero<<<1, 64, 0, stream>>>(bins);
  sort_hist<<<128, 256, 0, stream>>>(lens, bins);
  sort_scan<<<1, 64, 0, stream>>>(bins, offsw, bp, ctx, c0p);
  sort_scat<<<128, 256, 0, stream>>>(lens, offsw, permp);

  const size_t per_word = 20 * 128 * 2 * 2;  // hf+hb bytes per word
  size_t avail = (ws_size > H_OFF) ? (ws_size - H_OFF) : 0;
  int maxw = (int)(avail / per_word) & ~63;
  if (maxw > 32768) maxw = 32768;
  if (maxw < 64) maxw = 64;

  for (int done = 0; done < 32768;) {
    int nw = (32768 - done < maxw) ? (32768 - done) : maxw;
    u16* hfp = (u16*)(ws + H_OFF);
    u16* hbp = hfp + (size_t)nw * 2560;
    int nbd = nw / 16;
    gru_kernel<<<2 * nbd, 512, 0, stream>>>(chars, lens, permp, xpj_f, xpj_b,
                                            whhf, whhb, bhh_f, bhh_b, hfp, hbp,
                                            done, nbd);
    attn_kernel<<<nw / 16, 256, 0, stream>>>(hfp, hbp, wpf, bp, ctx, permp,
                                             lens, c0p, outp, done);
    done += nw;
  }
}